// Round 9
// baseline (153.036 us; speedup 1.0000x reference)
//
#include <hip/hip_runtime.h>
#include <cmath>

// Problem constants
#define NROWS 800        // BS*NQ
#define NCLS  81
#define MT    160        // targets
#define PPX   65536      // pixels per mask
#define SSPLIT 32        // K splits
#define CHUNK 2048       // PPX / SSPLIT
#define BK    64         // K per iteration
#define ITERS (CHUNK / BK)   // 32
#define RPB   32         // rows per block
#define RB    25         // row blocks (25*32 = 800 exact)

// Workspace layout (bytes)
#define OFF_TBF   0
#define SZ_TBF    (MT * PPX * 2)                 // 20,971,520 (bf16, natural layout)
#define OFF_CROSS (SZ_TBF)
#define OFF_SDOT  (OFF_CROSS + NROWS * MT * 4)
#define OFF_ROW   (OFF_SDOT + NROWS * MT * 4)
#define OFF_SSUM  (OFF_ROW + NROWS * 4)
#define OFF_TSUM  (OFF_SSUM + NROWS * 4)
#define OFF_PROB  (OFF_TSUM + MT * 4)
#define OFF_END   (OFF_PROB + NROWS * NCLS * 4)

typedef __attribute__((ext_vector_type(8))) short bf16x8;
typedef __attribute__((ext_vector_type(4))) float f32x4;

__device__ __forceinline__ unsigned short f2bf(float f) {
    unsigned int u = __float_as_uint(f);
    unsigned int r = (u + 0x7FFFu + ((u >> 16) & 1u)) >> 16;   // RNE
    return (unsigned short)r;
}

// ---------------------------------------------------------------------------
// Kernel 1: tgt_mask fp32 -> bf16 (NATURAL row-major; t is consumed straight
// from L2 into registers now, no LDS staging) + exact tsum[m].
// ---------------------------------------------------------------------------
__global__ __launch_bounds__(256) void prep_kernel(const float* __restrict__ tgt_mask,
                                                   char* __restrict__ ws) {
    int g = blockIdx.x * 256 + threadIdx.x;
    int m = g >> 13;            // 8192 8-px chunks per row
    int kc = g & 8191;
    const float4* src = (const float4*)(tgt_mask + (size_t)m * PPX + (kc << 3));
    float4 a = src[0], b = src[1];
    float part = a.x + a.y + a.z + a.w + b.x + b.y + b.z + b.w;

    uint4 o;
    o.x = (unsigned)f2bf(a.x) | ((unsigned)f2bf(a.y) << 16);
    o.y = (unsigned)f2bf(a.z) | ((unsigned)f2bf(a.w) << 16);
    o.z = (unsigned)f2bf(b.x) | ((unsigned)f2bf(b.y) << 16);
    o.w = (unsigned)f2bf(b.z) | ((unsigned)f2bf(b.w) << 16);
    *(uint4*)(ws + OFF_TBF + (size_t)m * (PPX * 2) + (size_t)kc * 16) = o;

    #pragma unroll
    for (int mk = 32; mk; mk >>= 1) part += __shfl_xor(part, mk);
    __shared__ float wsum[4];
    if ((threadIdx.x & 63) == 0) wsum[threadIdx.x >> 6] = part;
    __syncthreads();
    if (threadIdx.x == 0) {
        float tot = wsum[0] + wsum[1] + wsum[2] + wsum[3];
        atomicAdd((float*)(ws + OFF_TSUM) + m, tot);
    }
}

// ---------------------------------------------------------------------------
// Kernel 2: row softmax of pred_logits -> prob[800][81]
// ---------------------------------------------------------------------------
__global__ __launch_bounds__(64) void softmax_kernel(const float* __restrict__ logits,
                                                     float* __restrict__ prob) {
    int n = blockIdx.x;
    int l = threadIdx.x;
    const float* row = logits + n * NCLS;
    float v0 = row[l];
    float v1 = (l + 64 < NCLS) ? row[l + 64] : -INFINITY;
    float mx = fmaxf(v0, v1);
    #pragma unroll
    for (int mk = 32; mk; mk >>= 1) mx = fmaxf(mx, __shfl_xor(mx, mk));
    float e0 = __expf(v0 - mx);
    float e1 = (l + 64 < NCLS) ? __expf(v1 - mx) : 0.f;
    float s = e0 + e1;
    #pragma unroll
    for (int mk = 32; mk; mk >>= 1) s += __shfl_xor(s, mk);
    float inv = 1.f / s;
    prob[n * NCLS + l] = e0 * inv;
    if (l + 64 < NCLS) prob[n * NCLS + l + 64] = e1 * inv;
}

// ---------------------------------------------------------------------------
// Kernel 3: fused elementwise + dual GEMM (split-K). LDS-traffic-minimized:
//   - t fragments: L2 -> registers directly, double-buffered (TA/TB), no LDS.
//   - x/s: LDS double-buffered (ew8 computed ONCE, shared by all 4 waves).
//   - ONE barrier per half-iteration, no vmem drains (compiler tracks the
//     register-load dependencies exactly).
// Wave w owns 32 rows x col-tiles {3w..3w+2} (tiles >=10 clamp to 9, atomics
// skipped) -> no duplicate t reads across waves.
// ---------------------------------------------------------------------------
struct XS { float4 a; float4 b; };      // one iteration's 8 px (fp32)

__device__ __forceinline__ void loadx(XS& x, const float* xrow, int it) {
    const float* p = xrow + it * BK;
    x.a = *(const float4*)(p);
    x.b = *(const float4*)(p + 4);
}

// 8 px: e^v via exp2, sigmoid = t2/(1+t2), softplus accumulated in log2 units.
__device__ __forceinline__ void ew8(const XS& xs, bf16x8& xv, bf16x8& sv,
                                    float& slog2, float& sg_acc) {
    float vals[8] = {xs.a.x, xs.a.y, xs.a.z, xs.a.w, xs.b.x, xs.b.y, xs.b.z, xs.b.w};
    #pragma unroll
    for (int j = 0; j < 8; ++j) {
        float v = vals[j];
        float vl = fminf(v * 1.44269504089f, 126.f);         // overflow clamp
        float t2 = __builtin_amdgcn_exp2f(vl);               // e^v
        float d = 1.f + t2;
        float r = __builtin_amdgcn_rcpf(d);
        float sg = t2 * r;                                   // sigmoid(v)
        slog2 += __builtin_amdgcn_logf(d);                   // log2(1+e^v)
        sg_acc += sg;
        xv[j] = (short)f2bf(v);
        sv[j] = (short)f2bf(sg);
    }
}

__global__ __launch_bounds__(256) void main_kernel(const float* __restrict__ pred_masks,
                                                   char* __restrict__ ws) {
    __shared__ __align__(16) unsigned short lds_x[2][RPB * BK];  // 2 x 4096 B
    __shared__ __align__(16) unsigned short lds_s[2][RPB * BK];  // 2 x 4096 B

    const int tid = threadIdx.x;
    const int w = tid >> 6, l = tid & 63;
    const int rb = blockIdx.x >> 5;
    const int s = blockIdx.x & 31;       // bid%8 = s%8 -> same-s blocks share XCD L2
    const int k_base = s * CHUNK;

    // ---- x staging coords (thread: 1 row, 8 consecutive pixels)
    const int srow = tid >> 3;           // 0..31
    const int sc8 = tid & 7;             // 16B chunk within 64-px row
    const int n_glob = rb * RPB + srow;
    const float* xrow = pred_masks + (size_t)n_glob * PPX + k_base + sc8 * 8;
    const int xoff = srow * 128 + ((sc8 ^ (srow & 7)) * 16);   // swizzled byte off

    // ---- t fragment pointers: wave w covers col-tiles 3w..3w+2
    const unsigned short* tb = (const unsigned short*)(ws + OFF_TBF);
    const int lrow = l & 15;
    const int lk8 = (l >> 4) * 8;
    const unsigned short* tp[3];
    #pragma unroll
    for (int c = 0; c < 3; ++c) {
        int ctile = 3 * w + c;
        int crow = (ctile < 10 ? ctile : 9) * 16 + lrow;       // clamp pad tiles
        tp[c] = tb + (size_t)crow * PPX + k_base + lk8;
    }

    f32x4 accX[2][3], accS[2][3];
    #pragma unroll
    for (int rt = 0; rt < 2; ++rt)
        #pragma unroll
        for (int c = 0; c < 3; ++c) { accX[rt][c] = (f32x4)(0.f); accS[rt][c] = (f32x4)(0.f); }
    float slog2 = 0.f, rs_sg = 0.f;

    // register double buffers
    bf16x8 TA[2][3], TB[2][3];
    XS XA, XB;

    // prologue: t tile 0 -> TA; x tiles 0,1 -> XA,XB
    #pragma unroll
    for (int kk = 0; kk < 2; ++kk)
        #pragma unroll
        for (int c = 0; c < 3; ++c)
            TA[kk][c] = *(const bf16x8*)(tp[c] + kk * 32);
    loadx(XA, xrow, 0);
    loadx(XB, xrow, 1);

    #pragma unroll 1
    for (int it = 0; it < ITERS; it += 2) {
        // ================= half A: tile h=it, buf0, use XA/TA, fill TB ======
        {
            bf16x8 xv, sv;
            ew8(XA, xv, sv, slog2, rs_sg);
            *(bf16x8*)((char*)lds_x[0] + xoff) = xv;
            *(bf16x8*)((char*)lds_s[0] + xoff) = sv;
            asm volatile("s_waitcnt lgkmcnt(0)" ::: "memory");
            __builtin_amdgcn_sched_barrier(0);
            __builtin_amdgcn_s_barrier();
            __builtin_amdgcn_sched_barrier(0);

            const int tn = it + 1;                  // <= 31 always
            #pragma unroll
            for (int kk = 0; kk < 2; ++kk)
                #pragma unroll
                for (int c = 0; c < 3; ++c)
                    TB[kk][c] = *(const bf16x8*)(tp[c] + tn * BK + kk * 32);
            int tr = it + 2; if (tr >= ITERS) tr = ITERS - 1;
            loadx(XA, xrow, tr);
            __builtin_amdgcn_sched_barrier(0);

            #pragma unroll
            for (int rt = 0; rt < 2; ++rt)
                #pragma unroll
                for (int kk = 0; kk < 2; ++kk) {
                    const int arow = rt * 16 + lrow;
                    const int achunk = (kk * 4 + (l >> 4)) ^ (arow & 7);
                    bf16x8 ax = *(bf16x8*)((char*)lds_x[0] + arow * 128 + achunk * 16);
                    bf16x8 as_ = *(bf16x8*)((char*)lds_s[0] + arow * 128 + achunk * 16);
                    #pragma unroll
                    for (int c = 0; c < 3; ++c) {
                        accX[rt][c] = __builtin_amdgcn_mfma_f32_16x16x32_bf16(ax, TA[kk][c], accX[rt][c], 0, 0, 0);
                        accS[rt][c] = __builtin_amdgcn_mfma_f32_16x16x32_bf16(as_, TA[kk][c], accS[rt][c], 0, 0, 0);
                    }
                }
        }
        // ================= half B: tile it+1, buf1, use XB/TB, fill TA ======
        {
            bf16x8 xv, sv;
            ew8(XB, xv, sv, slog2, rs_sg);
            *(bf16x8*)((char*)lds_x[1] + xoff) = xv;
            *(bf16x8*)((char*)lds_s[1] + xoff) = sv;
            asm volatile("s_waitcnt lgkmcnt(0)" ::: "memory");
            __builtin_amdgcn_sched_barrier(0);
            __builtin_amdgcn_s_barrier();
            __builtin_amdgcn_sched_barrier(0);

            int tn = it + 2; if (tn >= ITERS) tn = ITERS - 1;
            #pragma unroll
            for (int kk = 0; kk < 2; ++kk)
                #pragma unroll
                for (int c = 0; c < 3; ++c)
                    TA[kk][c] = *(const bf16x8*)(tp[c] + tn * BK + kk * 32);
            int tr = it + 3; if (tr >= ITERS) tr = ITERS - 1;
            loadx(XB, xrow, tr);
            __builtin_amdgcn_sched_barrier(0);

            #pragma unroll
            for (int rt = 0; rt < 2; ++rt)
                #pragma unroll
                for (int kk = 0; kk < 2; ++kk) {
                    const int arow = rt * 16 + lrow;
                    const int achunk = (kk * 4 + (l >> 4)) ^ (arow & 7);
                    bf16x8 ax = *(bf16x8*)((char*)lds_x[1] + arow * 128 + achunk * 16);
                    bf16x8 as_ = *(bf16x8*)((char*)lds_s[1] + arow * 128 + achunk * 16);
                    #pragma unroll
                    for (int c = 0; c < 3; ++c) {
                        accX[rt][c] = __builtin_amdgcn_mfma_f32_16x16x32_bf16(ax, TB[kk][c], accX[rt][c], 0, 0, 0);
                        accS[rt][c] = __builtin_amdgcn_mfma_f32_16x16x32_bf16(as_, TB[kk][c], accS[rt][c], 0, 0, 0);
                    }
                }
        }
    }

    asm volatile("s_waitcnt vmcnt(0)" ::: "memory");

    // ---- row sums: reduce over the 8 lanes sharing a row, one atomic each
    float rs_sp = slog2 * 0.69314718056f;
    rs_sp += __shfl_xor(rs_sp, 1); rs_sp += __shfl_xor(rs_sp, 2); rs_sp += __shfl_xor(rs_sp, 4);
    rs_sg += __shfl_xor(rs_sg, 1); rs_sg += __shfl_xor(rs_sg, 2); rs_sg += __shfl_xor(rs_sg, 4);
    float* acc_row = (float*)(ws + OFF_ROW);
    float* acc_ssum = (float*)(ws + OFF_SSUM);
    if ((tid & 7) == 0) {
        atomicAdd(acc_row + n_glob, rs_sp);
        atomicAdd(acc_ssum + n_glob, rs_sg);
    }

    // ---- split-K accumulate the C fragments (skip pad col-tiles)
    float* acc_cross = (float*)(ws + OFF_CROSS);
    float* acc_sdot = (float*)(ws + OFF_SDOT);
    #pragma unroll
    for (int rt = 0; rt < 2; ++rt)
        #pragma unroll
        for (int c = 0; c < 3; ++c) {
            int ctile = 3 * w + c;
            if (ctile < 10) {
                int mcol = ctile * 16 + lrow;
                #pragma unroll
                for (int i = 0; i < 4; ++i) {
                    int nrow = rb * RPB + rt * 16 + (l >> 4) * 4 + i;
                    atomicAdd(acc_cross + nrow * MT + mcol, accX[rt][c][i]);
                    atomicAdd(acc_sdot + nrow * MT + mcol, accS[rt][c][i]);
                }
            }
        }
}

// ---------------------------------------------------------------------------
// Kernel 4: combine into C[n][m]
// ---------------------------------------------------------------------------
__global__ __launch_bounds__(256) void final_kernel(const int* __restrict__ tgt_ids,
                                                    const char* __restrict__ ws,
                                                    float* __restrict__ out) {
    int idx = blockIdx.x * 256 + threadIdx.x;   // 0..127999
    int n = idx / MT;
    int m = idx - n * MT;
    const float* prob = (const float*)(ws + OFF_PROB);
    const float* acc_cross = (const float*)(ws + OFF_CROSS);
    const float* acc_sdot = (const float*)(ws + OFF_SDOT);
    const float* acc_row = (const float*)(ws + OFF_ROW);
    const float* acc_ssum = (const float*)(ws + OFF_SSUM);
    const float* tsum = (const float*)(ws + OFF_TSUM);

    float cls = -prob[n * NCLS + tgt_ids[m]];
    float cmask = (acc_row[n] - acc_cross[idx]) * (1.f / PPX);
    float cdice = 1.f - (2.f * acc_sdot[idx] + 1.f) / (acc_ssum[n] + tsum[m] + 1.f);
    out[idx] = cls + cmask + cdice;
}

extern "C" void kernel_launch(void* const* d_in, const int* in_sizes, int n_in,
                              void* d_out, int out_size, void* d_ws, size_t ws_size,
                              hipStream_t stream) {
    const float* pred_logits = (const float*)d_in[0];
    const float* pred_masks  = (const float*)d_in[1];
    const int*   tgt_ids     = (const int*)d_in[2];
    const float* tgt_mask    = (const float*)d_in[3];
    char* ws = (char*)d_ws;

    (void)hipMemsetAsync(ws + OFF_CROSS, 0, OFF_END - OFF_CROSS, stream);
    prep_kernel<<<5120, 256, 0, stream>>>(tgt_mask, ws);
    softmax_kernel<<<NROWS, 64, 0, stream>>>(pred_logits, (float*)(ws + OFF_PROB));
    main_kernel<<<RB * SSPLIT, 256, 0, stream>>>(pred_masks, ws);
    final_kernel<<<500, 256, 0, stream>>>(tgt_ids, ws, (float*)d_out);
}